// Round 5
// baseline (174.272 us; speedup 1.0000x reference)
//
#include <hip/hip_runtime.h>
#include <hip/hip_bf16.h>
#include <math.h>

typedef __attribute__((ext_vector_type(4))) float  f32x4;
typedef __attribute__((ext_vector_type(8))) short  short8;
typedef __attribute__((ext_vector_type(4))) short  short4_t;

#define DTC   0.1f
#define EPSF  1e-6f
// lower-triangle (i>=j) of 64x64: 2080 pairs, padded to 2176 = 17*128 packed cols
#define NPACK 2176
#define NTRI  2080

static __device__ __forceinline__ unsigned short f2bf(float f) {
    union { float f; unsigned int u; } v; v.f = f;
    unsigned int u = v.u;
    return (unsigned short)((u + 0x7FFFu + ((u >> 16) & 1u)) >> 16);  // RNE
}
static __device__ __forceinline__ unsigned short f2bf_hw(float f) {
    __hip_bfloat16 b = __float2bfloat16(f);
    union { __hip_bfloat16 b; unsigned short u; } v; v.b = b;
    return v.u;
}
static __device__ __forceinline__ float bf2f(unsigned short b) {
    union { unsigned int u; float f; } v; v.u = ((unsigned int)b) << 16;
    return v.f;
}
// packed index p (0..2079) -> (i,j), i>=j. Row r pairs diag r (len 64-r) with
// diag 63-r (len r+1): 32 rows * 65 = 2080.
static __device__ __forceinline__ void tri_unpack(int p, int& i, int& j) {
    int r = p / 65, c = p - r * 65;
    if (c < 64 - r) { j = c;            i = c + r;       }
    else            { j = c - 64 + r;   i = j + 63 - r;  }
}

static __device__ __forceinline__ void gload_lds16(const void* gptr, void* ldsptr) {
    __builtin_amdgcn_global_load_lds(
        (const __attribute__((address_space(1))) unsigned int*)gptr,
        (__attribute__((address_space(3))) unsigned int*)ldsptr, 16, 0, 0);
}

// ---------------- pack: W1 -> bf16 ; W2/b2 -> lower-tri-packed bf16/f32 rows
__global__ __launch_bounds__(256) void pack_k(const float* __restrict__ W1,
                                              const float* __restrict__ W2,
                                              const float* __restrict__ b2,
                                              unsigned short* __restrict__ w1b,
                                              unsigned short* __restrict__ w2p,
                                              float* __restrict__ b2p) {
    const int bid = blockIdx.x, t = threadIdx.x;
    if (bid < 1024) {                       // W1: 1,048,576 f32 = 262,144 f32x4
        int idx = bid * 256 + t;
        f32x4 v = ((const f32x4*)W1)[idx];
        short4_t o;
        o[0] = (short)f2bf(v[0]); o[1] = (short)f2bf(v[1]);
        o[2] = (short)f2bf(v[2]); o[3] = (short)f2bf(v[3]);
        ((short4_t*)w1b)[idx] = o;
    } else {                                // one block per packed row p
        int p = bid - 1024;                 // 0..2175
        if (p < NTRI) {
            int i, j; tri_unpack(p, i, j);
            w2p[p * 256 + t] = f2bf(W2[(i * 64 + j) * 256L + t]);
            if (t == 0) b2p[p] = b2[i * 64 + j];
        } else {
            w2p[p * 256 + t] = 0;
            if (t == 0) b2p[p] = 0.f;
        }
    }
}

// --- fused GEMM1: h = tanh(metric_f32 @ W1bf^T + b1) -> bf16 [8192,256]
// BM=32, BN=256 (full), K=4096, 512 threads (8 waves, each 32x32 out tile),
// double-buffered LDS, stage(t+1)-before-compute(t) 2-phase pipeline.
__global__ __launch_bounds__(512, 2) void gemm1f_k(const float* __restrict__ A,
                                                   const unsigned short* __restrict__ B,
                                                   const float* __restrict__ b1,
                                                   unsigned short* __restrict__ h) {
    __shared__ unsigned short As[2][32 * 64];    // 2 x 4 KB
    __shared__ unsigned short Bs[2][256 * 64];   // 2 x 32 KB
    const int tid  = threadIdx.x;
    const int lane = tid & 63;
    const int w    = tid >> 6;                   // 0..7, wave n-tile
    const long bm  = (long)blockIdx.x * 32;

    f32x4 acc[2][2];
#pragma unroll
    for (int m = 0; m < 2; m++)
#pragma unroll
        for (int n = 0; n < 2; n++) acc[m][n] = (f32x4){0.f, 0.f, 0.f, 0.f};

    const int arow = tid >> 4;          // 0..31
    const int acol = (tid & 15) * 4;    // 0..60
    const int brow = tid >> 3;          // 0..63
    const int bcol = (tid & 7) * 8;     // 0..56

    // prologue: stage K-step 0 into buffer 0
    {
        f32x4 a0 = *(const f32x4*)(A + (bm + arow) * 4096L + acol);
#pragma unroll
        for (int i = 0; i < 4; i++)
            gload_lds16(B + (i * 64 + brow) * 4096L + bcol,
                        (char*)&Bs[0][0] + i * 8192 + tid * 16);
        short4_t o;
#pragma unroll
        for (int e = 0; e < 4; e++) o[e] = (short)f2bf_hw(a0[e]);
        *(short4_t*)&As[0][arow * 64 + acol] = o;
    }
    __syncthreads();

    for (int t = 0; t < 63; t++) {
        const int cur = t & 1, nxt = cur ^ 1;
        const int kk = (t + 1) * 64;
        // issue next tile's loads first (overlap with this tile's compute)
        f32x4 an = *(const f32x4*)(A + (bm + arow) * 4096L + kk + acol);
#pragma unroll
        for (int i = 0; i < 4; i++)
            gload_lds16(B + (i * 64 + brow) * 4096L + kk + bcol,
                        (char*)&Bs[nxt][0] + i * 8192 + tid * 16);
        // compute current tile
        short8 af[2][2], bf[2][2];
#pragma unroll
        for (int m = 0; m < 2; m++)
#pragma unroll
            for (int kq = 0; kq < 2; kq++)
                af[m][kq] = *(const short8*)&As[cur][(m * 16 + (lane & 15)) * 64 +
                                                     kq * 32 + (lane >> 4) * 8];
#pragma unroll
        for (int n = 0; n < 2; n++)
#pragma unroll
            for (int kq = 0; kq < 2; kq++)
                bf[n][kq] = *(const short8*)&Bs[cur][(w * 32 + n * 16 + (lane & 15)) * 64 +
                                                     kq * 32 + (lane >> 4) * 8];
#pragma unroll
        for (int m = 0; m < 2; m++)
#pragma unroll
            for (int n = 0; n < 2; n++) {
                acc[m][n] = __builtin_amdgcn_mfma_f32_16x16x32_bf16(af[m][0], bf[n][0],
                                                                    acc[m][n], 0, 0, 0);
                acc[m][n] = __builtin_amdgcn_mfma_f32_16x16x32_bf16(af[m][1], bf[n][1],
                                                                    acc[m][n], 0, 0, 0);
            }
        // land next A tile (forces vmcnt wait on an; Bs[nxt] drained by barrier)
        short4_t o;
#pragma unroll
        for (int e = 0; e < 4; e++) o[e] = (short)f2bf_hw(an[e]);
        *(short4_t*)&As[nxt][arow * 64 + acol] = o;
        __syncthreads();
    }
    // final tile (buffer 63 & 1 = 1)
    {
        short8 af[2][2], bf[2][2];
#pragma unroll
        for (int m = 0; m < 2; m++)
#pragma unroll
            for (int kq = 0; kq < 2; kq++)
                af[m][kq] = *(const short8*)&As[1][(m * 16 + (lane & 15)) * 64 +
                                                   kq * 32 + (lane >> 4) * 8];
#pragma unroll
        for (int n = 0; n < 2; n++)
#pragma unroll
            for (int kq = 0; kq < 2; kq++)
                bf[n][kq] = *(const short8*)&Bs[1][(w * 32 + n * 16 + (lane & 15)) * 64 +
                                                   kq * 32 + (lane >> 4) * 8];
#pragma unroll
        for (int m = 0; m < 2; m++)
#pragma unroll
            for (int n = 0; n < 2; n++) {
                acc[m][n] = __builtin_amdgcn_mfma_f32_16x16x32_bf16(af[m][0], bf[n][0],
                                                                    acc[m][n], 0, 0, 0);
                acc[m][n] = __builtin_amdgcn_mfma_f32_16x16x32_bf16(af[m][1], bf[n][1],
                                                                    acc[m][n], 0, 0, 0);
            }
    }

    // epilogue: h = tanh(acc + b1), bf16
#pragma unroll
    for (int n = 0; n < 2; n++) {
        int col = w * 32 + n * 16 + (lane & 15);
        float bv = b1[col];
#pragma unroll
        for (int m = 0; m < 2; m++)
#pragma unroll
            for (int r = 0; r < 4; r++) {
                long row = bm + m * 16 + (lane >> 4) * 4 + r;
                h[row * 256 + col] = f2bf(tanhf(acc[m][n][r] + bv));
            }
    }
}

// ------------------- GEMM2 packed: mlpP[8192,2176] = h @ W2p^T + b2p -> bf16
__global__ __launch_bounds__(256, 2) void gemm2p_k(const unsigned short* __restrict__ A,
                                                   const unsigned short* __restrict__ B,
                                                   const float* __restrict__ bias,
                                                   unsigned short* __restrict__ C) {
    __shared__ unsigned short As[128 * 64];
    __shared__ unsigned short Bs[128 * 64];
    const int tid  = threadIdx.x;
    const int lane = tid & 63;
    const int w    = tid >> 6;
    const int wm   = w >> 1, wn = w & 1;
    const long bm  = (long)blockIdx.x * 128;
    const long bn  = (long)blockIdx.y * 128;   // < 2176

    f32x4 acc[4][4];
#pragma unroll
    for (int m = 0; m < 4; m++)
#pragma unroll
        for (int n = 0; n < 4; n++) acc[m][n] = (f32x4){0.f, 0.f, 0.f, 0.f};

    const int r0 = tid >> 3;
    const int c0 = (tid & 7) * 8;

    for (int kk = 0; kk < 256; kk += 64) {
#pragma unroll
        for (int i = 0; i < 4; i++) {
            gload_lds16(A + (bm + i * 32 + r0) * 256L + kk + c0,
                        (char*)As + i * 4096 + tid * 16);
            gload_lds16(B + (bn + i * 32 + r0) * 256L + kk + c0,
                        (char*)Bs + i * 4096 + tid * 16);
        }
        __syncthreads();

        short8 af[4][2], bf[4][2];
#pragma unroll
        for (int m = 0; m < 4; m++)
#pragma unroll
            for (int kq = 0; kq < 2; kq++)
                af[m][kq] = *(const short8*)&As[(wm * 64 + m * 16 + (lane & 15)) * 64 +
                                                kq * 32 + (lane >> 4) * 8];
#pragma unroll
        for (int n = 0; n < 4; n++)
#pragma unroll
            for (int kq = 0; kq < 2; kq++)
                bf[n][kq] = *(const short8*)&Bs[(wn * 64 + n * 16 + (lane & 15)) * 64 +
                                                kq * 32 + (lane >> 4) * 8];
#pragma unroll
        for (int m = 0; m < 4; m++)
#pragma unroll
            for (int n = 0; n < 4; n++) {
                acc[m][n] = __builtin_amdgcn_mfma_f32_16x16x32_bf16(af[m][0], bf[n][0],
                                                                    acc[m][n], 0, 0, 0);
                acc[m][n] = __builtin_amdgcn_mfma_f32_16x16x32_bf16(af[m][1], bf[n][1],
                                                                    acc[m][n], 0, 0, 0);
            }
        __syncthreads();
    }

#pragma unroll
    for (int n = 0; n < 4; n++) {
        long col = bn + wn * 64 + n * 16 + (lane & 15);
        float bv = bias[col];
#pragma unroll
        for (int m = 0; m < 4; m++)
#pragma unroll
            for (int r = 0; r < 4; r++) {
                long row = bm + wm * 64 + m * 16 + (lane >> 4) * 4 + r;
                C[row * NPACK + col] = f2bf(acc[m][n][r] + bv);
            }
    }
}

// ---- finalize: scatter packed mlp -> tri LDS; norms -> adt; out = metric + adt*F_sym
__global__ __launch_bounds__(256) void finalize3_k(const float* __restrict__ metric,
                                                   const float* __restrict__ ricci,
                                                   const unsigned short* __restrict__ mlpP,
                                                   float* __restrict__ out) {
    const int b = blockIdx.x;
    const int t = threadIdx.x;
    const long mbase = (long)b * 4096;
    const long pbase = (long)b * NPACK;
    __shared__ float s_f[64 * 65];  // lower-tri values live at [i*65 + j], j<=i
    __shared__ float red[8];
    __shared__ float s_adt;

    // phase 1: scatter packed mlp (bf16) into s_f
    const short8* mp8 = (const short8*)(mlpP + pbase);
    {
        short8 v = mp8[t];                       // p = t*8 .. t*8+7  (< 2048)
#pragma unroll
        for (int e = 0; e < 8; e++) {
            int p = t * 8 + e, i, j;
            tri_unpack(p, i, j);
            s_f[i * 65 + j] = bf2f((unsigned short)v[e]);
        }
        if (t < 4) {                             // p = 2048 .. 2079
            short8 v2 = mp8[256 + t];
#pragma unroll
            for (int e = 0; e < 8; e++) {
                int p = 2048 + t * 8 + e, i, j;
                tri_unpack(p, i, j);
                s_f[i * 65 + j] = bf2f((unsigned short)v2[e]);
            }
        }
    }
    __syncthreads();

    // phase 2: norms + fold -2*ricci into lower-tri slots (unique owner per slot)
    const f32x4* met4 = (const f32x4*)(metric + mbase);
    const f32x4* ric4 = (const f32x4*)(ricci + mbase);
    f32x4 mm[4];
    float msq = 0.f, rsq = 0.f;
#pragma unroll
    for (int k = 0; k < 4; k++) {
        int v = k * 256 + t;
        f32x4 r = ric4[v];
        f32x4 m = met4[v];
        mm[k] = m;
        msq += m[0]*m[0] + m[1]*m[1] + m[2]*m[2] + m[3]*m[3];
        rsq += r[0]*r[0] + r[1]*r[1] + r[2]*r[2] + r[3]*r[3];
        int e0 = v * 4;
        int i = e0 >> 6, j0 = e0 & 63;
#pragma unroll
        for (int e = 0; e < 4; e++) {
            int j = j0 + e;
            if (j <= i) s_f[i * 65 + j] -= 2.f * r[e];
        }
    }
#pragma unroll
    for (int off = 32; off > 0; off >>= 1) {
        msq += __shfl_down(msq, off);
        rsq += __shfl_down(rsq, off);
    }
    if ((t & 63) == 0) { red[t >> 6] = msq; red[4 + (t >> 6)] = rsq; }
    __syncthreads();
    if (t == 0) {
        float tm = red[0] + red[1] + red[2] + red[3];
        float tr = red[4] + red[5] + red[6] + red[7];
        s_adt = DTC * fminf(1.0f, 0.1f * sqrtf(tm) / (sqrtf(tr) + EPSF));
    }
    __syncthreads();

    // phase 3: out = metric + adt * F[max][min]
    const float adt = s_adt;
    f32x4* out4 = (f32x4*)(out + mbase);
#pragma unroll
    for (int k = 0; k < 4; k++) {
        int v = k * 256 + t;
        int e0 = v * 4;
        int i = e0 >> 6, j0 = e0 & 63;
        f32x4 o;
#pragma unroll
        for (int e = 0; e < 4; e++) {
            int j = j0 + e;
            int mx = i > j ? i : j;
            int mn = i > j ? j : i;
            o[e] = mm[k][e] + adt * s_f[mx * 65 + mn];
        }
        out4[v] = o;
    }
}

// ---------------------------------------------------------------------- launcher
extern "C" void kernel_launch(void* const* d_in, const int* in_sizes, int n_in,
                              void* d_out, int out_size, void* d_ws, size_t ws_size,
                              hipStream_t stream) {
    const float* metric = (const float*)d_in[0];  // [8192,64,64]
    const float* ricci  = (const float*)d_in[1];  // [8192,64,64]
    const float* W1     = (const float*)d_in[2];  // [256,4096]
    const float* b1     = (const float*)d_in[3];  // [256]
    const float* W2     = (const float*)d_in[4];  // [4096,256]
    const float* b2     = (const float*)d_in[5];  // [4096]
    float* out = (float*)d_out;

    const int B = 8192;

    char* ws = (char*)d_ws;
    unsigned short* mlpP = (unsigned short*)(ws);                // 8192*2176*2 = 35,651,584
    unsigned short* w1b  = (unsigned short*)(ws + 35651584);     // 2,097,152
    unsigned short* w2p  = (unsigned short*)(ws + 37748736);     // 2176*256*2 = 1,114,112
    float*          b2p  = (float*)(ws + 38862848);              // 2176*4     = 8,704
    unsigned short* hbf  = (unsigned short*)(ws + 38871552);     // 8192*256*2 = 4,194,304

    // pack/cast weights (W1 cast: blocks 0..1023; W2/b2 tri-pack: blocks 1024..3199)
    pack_k<<<dim3(1024 + NPACK), dim3(256), 0, stream>>>(W1, W2, b2, w1b, w2p, b2p);

    // h = tanh(metric @ W1^T + b1), fused full-K GEMM, 256 blocks x 512 threads
    gemm1f_k<<<dim3(B / 32), dim3(512), 0, stream>>>(metric, w1b, b1, hbf);
    // mlpP = h @ W2p^T + b2p -> bf16 packed lower-tri columns
    gemm2p_k<<<dim3(B / 128, NPACK / 128), dim3(256), 0, stream>>>(hbf, w2p, b2p, mlpP);
    // out = metric + adt * sym_lower(-2*ricci + mlp)
    finalize3_k<<<dim3(B), dim3(256), 0, stream>>>(metric, ricci, mlpP, out);

    (void)in_sizes; (void)n_in; (void)out_size; (void)ws_size;
}